// Round 1
// baseline (183.109 us; speedup 1.0000x reference)
//
#include <hip/hip_runtime.h>
#include <hip/hip_bf16.h>
#include <stdint.h>

#define B_   4
#define SEQ_ 1024
#define DM   1024
#define H_   16
#define HD   64

typedef __bf16 bf16;
typedef __bf16 bf16x8 __attribute__((ext_vector_type(8)));
typedef __bf16 bf16x4v __attribute__((ext_vector_type(4)));
typedef float  f32x4 __attribute__((ext_vector_type(4)));

__device__ __forceinline__ void gl_lds16(const void* g, void* s_uniform) {
    __builtin_amdgcn_global_load_lds(
        (const __attribute__((address_space(1))) uint32_t*)g,
        (__attribute__((address_space(3))) uint32_t*)s_uniform,
        16, 0, 0);
}

// ---------------------------------------------------------------------------
// prep: fp32 -> bf16 casts + T5 relative-position bias table [h][dist]
// ---------------------------------------------------------------------------
__global__ __launch_bounds__(256) void prep_kernel(
    const float* __restrict__ x, const float* __restrict__ Wq,
    const float* __restrict__ Wk, const float* __restrict__ Wv,
    const float* __restrict__ Wo, const float* __restrict__ rel,
    bf16* __restrict__ xb, bf16* __restrict__ wqkvb, bf16* __restrict__ wob,
    float* __restrict__ biasT)
{
    int tid = blockIdx.x * 256 + threadIdx.x;
    int stride = gridDim.x * 256;

    // x: (4096,1024) fp32 -> bf16, as float4 chunks
    for (int i = tid; i < (B_*SEQ_*DM)/4; i += stride) {
        float4 v = ((const float4*)x)[i];
        bf16x4v o; o[0]=(bf16)v.x; o[1]=(bf16)v.y; o[2]=(bf16)v.z; o[3]=(bf16)v.w;
        ((bf16x4v*)xb)[i] = o;
    }
    // Wq|Wk|Wv packed -> (3072,1024) bf16 (row n, contraction k)
    for (int i = tid; i < (3*DM*DM)/4; i += stride) {
        int n = i >> 8, k4 = i & 255;
        const float* src = (n < 1024) ? Wq : (n < 2048) ? Wk : Wv;
        float4 v = ((const float4*)(src + (size_t)(n & 1023) * DM))[k4];
        bf16x4v o; o[0]=(bf16)v.x; o[1]=(bf16)v.y; o[2]=(bf16)v.z; o[3]=(bf16)v.w;
        ((bf16x4v*)wqkvb)[i] = o;
    }
    // Wo -> bf16
    for (int i = tid; i < (DM*DM)/4; i += stride) {
        float4 v = ((const float4*)Wo)[i];
        bf16x4v o; o[0]=(bf16)v.x; o[1]=(bf16)v.y; o[2]=(bf16)v.z; o[3]=(bf16)v.w;
        ((bf16x4v*)wob)[i] = o;
    }
    // bias table: biasT[h*1024 + dist] = rel[bucket(dist)*16 + h] * 0.125
    for (int i = tid; i < H_ * SEQ_; i += stride) {
        int h = i >> 10, dist = i & 1023;
        int bkt;
        if (dist < 16) {
            bkt = dist;
        } else {
            float r = logf((float)dist * (1.0f/16.0f)) / logf(8.0f) * 16.0f;
            int vb = 16 + (int)r;          // trunc toward zero, matches astype(int32)
            bkt = vb > 31 ? 31 : vb;
        }
        biasT[i] = rel[bkt * H_ + h] * 0.125f;
    }
}

// ---------------------------------------------------------------------------
// GEMM C = A @ B^T  (both A and B K-contiguous, bf16, fp32 accumulate)
// 128x128 tile, BK=64, 256 threads (4 waves, 2x2 of 64x64), mfma 16x16x32
// MODE 0: QKV epilogue -> scatter to Q(b,h,n,d), K(b,h,n,d), Vt(b,h,d,n) bf16
// MODE 1: out epilogue -> fp32 C + bias
// ---------------------------------------------------------------------------
template<int MODE>
__global__ __launch_bounds__(256) void gemm_bt(
    const bf16* __restrict__ A, const bf16* __restrict__ Bm, int K,
    bf16* __restrict__ qb, bf16* __restrict__ kb, bf16* __restrict__ vtb,
    const float* __restrict__ bq, const float* __restrict__ bk,
    const float* __restrict__ bv,
    float* __restrict__ outp, const float* __restrict__ bo, int Nout)
{
    __shared__ __align__(16) bf16 As[128 * 64];
    __shared__ __align__(16) bf16 Bs[128 * 64];

    int t = threadIdx.x;
    int lane = t & 63, w = t >> 6;
    int wr = w >> 1, wc = w & 1;
    int m0 = blockIdx.y * 128, n0 = blockIdx.x * 128;
    int row_l = lane & 15;
    int ksl = (lane >> 4) * 8;

    f32x4 acc[4][4] = {};

    for (int k0 = 0; k0 < K; k0 += 64) {
        #pragma unroll
        for (int i = 0; i < 4; ++i) {
            int e = i * 2048 + t * 8;
            int r = e >> 6, c = e & 63;
            gl_lds16(A  + (long)(m0 + r) * K + k0 + c, &As[i * 2048 + w * 512]);
            gl_lds16(Bm + (long)(n0 + r) * K + k0 + c, &Bs[i * 2048 + w * 512]);
        }
        __syncthreads();
        #pragma unroll
        for (int kk = 0; kk < 2; ++kk) {
            bf16x8 af[4], bfr[4];
            #pragma unroll
            for (int mi = 0; mi < 4; ++mi)
                af[mi] = *(const bf16x8*)&As[(wr*64 + mi*16 + row_l)*64 + kk*32 + ksl];
            #pragma unroll
            for (int ni = 0; ni < 4; ++ni)
                bfr[ni] = *(const bf16x8*)&Bs[(wc*64 + ni*16 + row_l)*64 + kk*32 + ksl];
            #pragma unroll
            for (int mi = 0; mi < 4; ++mi)
                #pragma unroll
                for (int ni = 0; ni < 4; ++ni)
                    acc[mi][ni] = __builtin_amdgcn_mfma_f32_16x16x32_bf16(
                        af[mi], bfr[ni], acc[mi][ni], 0, 0, 0);
        }
        __syncthreads();
    }

    int rbase = (lane >> 4) * 4;
    #pragma unroll
    for (int mi = 0; mi < 4; ++mi) {
        #pragma unroll
        for (int ni = 0; ni < 4; ++ni) {
            #pragma unroll
            for (int g = 0; g < 4; ++g) {
                int m = m0 + wr*64 + mi*16 + rbase + g;
                int n = n0 + wc*64 + ni*16 + (lane & 15);
                float v = acc[mi][ni][g];
                if (MODE == 0) {
                    int which = n >> 10, nn = n & 1023;
                    int h = nn >> 6, d = nn & 63;
                    int b = m >> 10, s = m & 1023;
                    const float* bias = (which == 0) ? bq : (which == 1) ? bk : bv;
                    v += bias[nn];
                    bf16 bv16 = (bf16)v;
                    if (which == 0)
                        qb[((long)(b*H_ + h)*SEQ_ + s)*HD + d] = bv16;
                    else if (which == 1)
                        kb[((long)(b*H_ + h)*SEQ_ + s)*HD + d] = bv16;
                    else
                        vtb[((long)(b*H_ + h)*HD + d)*SEQ_ + s] = bv16;
                } else {
                    outp[(long)m * Nout + n] = v + bo[n];
                }
            }
        }
    }
}

// ---------------------------------------------------------------------------
// Flash attention: per (qtile 64, b*h). 4 waves x 16 q-rows.
// S = Q K^T (unscaled) + bias(dist)*0.125 + causal; online softmax; O = P V.
// ---------------------------------------------------------------------------
__global__ __launch_bounds__(256) void attn_kernel(
    const bf16* __restrict__ Qb, const bf16* __restrict__ Kb,
    const bf16* __restrict__ Vtb, const float* __restrict__ biasT,
    bf16* __restrict__ AO)
{
    __shared__ __align__(16) bf16 Ks[64 * 64];
    __shared__ __align__(16) bf16 Vs[64 * 64];
    __shared__ __align__(16) bf16 Ps[4][16 * 64];
    __shared__ float biasS[SEQ_];

    int t = threadIdx.x;
    int lane = t & 63, w = t >> 6;
    int qt = blockIdx.x, bh = blockIdx.y;
    int h = bh & 15, b = bh >> 4;
    int q0 = qt * 64;
    int row_l = lane & 15;
    int ksl = (lane >> 4) * 8;
    int rbase = (lane >> 4) * 4;

    // stage this head's bias row (1024 f32) into LDS
    ((float4*)biasS)[t] = ((const float4*)(biasT + (long)h * SEQ_))[t];

    // Q fragments held in registers for the whole block
    const bf16* Qp = Qb + ((long)bh * SEQ_ + q0 + w * 16) * HD;
    bf16x8 qf0 = *(const bf16x8*)&Qp[row_l * HD + ksl];
    bf16x8 qf1 = *(const bf16x8*)&Qp[row_l * HD + 32 + ksl];

    f32x4 oacc[4] = {};
    float m_run[4], l_run[4];
    int i_row[4];
    #pragma unroll
    for (int g = 0; g < 4; ++g) {
        m_run[g] = -1e30f; l_run[g] = 0.f;
        i_row[g] = q0 + w * 16 + rbase + g;
    }

    const bf16* Kbase = Kb + (long)bh * SEQ_ * HD;
    const bf16* Vbase = Vtb + (long)bh * HD * SEQ_;

    for (int jt = 0; jt <= qt; ++jt) {
        #pragma unroll
        for (int i = 0; i < 2; ++i) {
            int e = i * 2048 + t * 8;
            gl_lds16(Kbase + (long)jt * 64 * HD + e, &Ks[i * 2048 + w * 512]);
            int r = e >> 6, c = e & 63;
            gl_lds16(Vbase + (long)r * SEQ_ + jt * 64 + c, &Vs[i * 2048 + w * 512]);
        }
        __syncthreads();

        // S = Q K^T
        f32x4 sacc[4] = {};
        #pragma unroll
        for (int f = 0; f < 4; ++f) {
            bf16x8 kf0 = *(const bf16x8*)&Ks[(f*16 + row_l)*64 + ksl];
            bf16x8 kf1 = *(const bf16x8*)&Ks[(f*16 + row_l)*64 + 32 + ksl];
            sacc[f] = __builtin_amdgcn_mfma_f32_16x16x32_bf16(qf0, kf0, sacc[f], 0,0,0);
            sacc[f] = __builtin_amdgcn_mfma_f32_16x16x32_bf16(qf1, kf1, sacc[f], 0,0,0);
        }

        // bias + causal mask
        float s_v[4][4];
        #pragma unroll
        for (int f = 0; f < 4; ++f) {
            int j = jt * 64 + f * 16 + (lane & 15);
            #pragma unroll
            for (int g = 0; g < 4; ++g) {
                int i_ = i_row[g];
                s_v[f][g] = (j <= i_) ? (sacc[f][g] + biasS[i_ - j]) : -1e30f;
            }
        }

        // online softmax (row reductions over 4 frags + 16-lane butterfly)
        float pv[4][4], sc_a[4];
        #pragma unroll
        for (int g = 0; g < 4; ++g) {
            float mx = fmaxf(fmaxf(s_v[0][g], s_v[1][g]), fmaxf(s_v[2][g], s_v[3][g]));
            #pragma unroll
            for (int off = 1; off < 16; off <<= 1) mx = fmaxf(mx, __shfl_xor(mx, off));
            float mnew = fmaxf(m_run[g], mx);
            float sc = __expf(m_run[g] - mnew);
            float rs = 0.f;
            #pragma unroll
            for (int f = 0; f < 4; ++f) {
                float p = __expf(s_v[f][g] - mnew);
                pv[f][g] = p; rs += p;
            }
            #pragma unroll
            for (int off = 1; off < 16; off <<= 1) rs += __shfl_xor(rs, off);
            l_run[g] = l_run[g] * sc + rs;
            m_run[g] = mnew;
            sc_a[g] = sc;
        }
        #pragma unroll
        for (int db = 0; db < 4; ++db)
            #pragma unroll
            for (int g = 0; g < 4; ++g)
                oacc[db][g] *= sc_a[g];

        // P (C-layout) -> per-wave LDS -> A-layout fragments
        #pragma unroll
        for (int f = 0; f < 4; ++f)
            #pragma unroll
            for (int g = 0; g < 4; ++g)
                Ps[w][(rbase + g) * 64 + f * 16 + (lane & 15)] = (bf16)pv[f][g];

        bf16x8 pf0 = *(const bf16x8*)&Ps[w][row_l * 64 + ksl];
        bf16x8 pf1 = *(const bf16x8*)&Ps[w][row_l * 64 + 32 + ksl];

        // O += P V   (B-operand from Vt tile, contiguous reads)
        #pragma unroll
        for (int db = 0; db < 4; ++db) {
            bf16x8 vf0 = *(const bf16x8*)&Vs[(db*16 + row_l)*64 + ksl];
            bf16x8 vf1 = *(const bf16x8*)&Vs[(db*16 + row_l)*64 + 32 + ksl];
            oacc[db] = __builtin_amdgcn_mfma_f32_16x16x32_bf16(pf0, vf0, oacc[db], 0,0,0);
            oacc[db] = __builtin_amdgcn_mfma_f32_16x16x32_bf16(pf1, vf1, oacc[db], 0,0,0);
        }
        __syncthreads();
    }

    // epilogue: O/l -> AO (b, n, h*64+d) bf16
    #pragma unroll
    for (int g = 0; g < 4; ++g) {
        float inv = 1.0f / l_run[g];
        long base = ((long)(b * SEQ_ + i_row[g])) * DM + h * HD;
        #pragma unroll
        for (int db = 0; db < 4; ++db)
            AO[base + db * 16 + (lane & 15)] = (bf16)(oacc[db][g] * inv);
    }
}

// ---------------------------------------------------------------------------
extern "C" void kernel_launch(void* const* d_in, const int* in_sizes, int n_in,
                              void* d_out, int out_size, void* d_ws, size_t ws_size,
                              hipStream_t stream)
{
    const float* x   = (const float*)d_in[0];
    const float* Wq  = (const float*)d_in[1];
    const float* bq  = (const float*)d_in[2];
    const float* Wk  = (const float*)d_in[3];
    const float* bk  = (const float*)d_in[4];
    const float* Wv  = (const float*)d_in[5];
    const float* bv  = (const float*)d_in[6];
    const float* Wo  = (const float*)d_in[7];
    const float* bo  = (const float*)d_in[8];
    const float* rel = (const float*)d_in[9];
    float* out = (float*)d_out;

    char* ws = (char*)d_ws;
    bf16* xb    = (bf16*)ws;  ws += (size_t)B_*SEQ_*DM * 2;     // 8 MB
    bf16* wqkvb = (bf16*)ws;  ws += (size_t)3*DM*DM * 2;        // 6 MB
    bf16* wob   = (bf16*)ws;  ws += (size_t)DM*DM * 2;          // 2 MB
    float* biasT= (float*)ws; ws += (size_t)H_*SEQ_ * 4;        // 64 KB
    bf16* Qb    = (bf16*)ws;  ws += (size_t)B_*H_*SEQ_*HD * 2;  // 8 MB
    bf16* Kb2   = (bf16*)ws;  ws += (size_t)B_*H_*SEQ_*HD * 2;  // 8 MB
    bf16* Vtb   = (bf16*)ws;  ws += (size_t)B_*H_*SEQ_*HD * 2;  // 8 MB
    bf16* AO    = (bf16*)ws;  ws += (size_t)B_*SEQ_*DM * 2;     // 8 MB

    prep_kernel<<<2048, 256, 0, stream>>>(x, Wq, Wk, Wv, Wo, rel,
                                          xb, wqkvb, wob, biasT);

    dim3 g1(24, 32);  // N=3072 tiles x M=4096 tiles
    gemm_bt<0><<<g1, 256, 0, stream>>>(xb, wqkvb, DM,
                                       Qb, Kb2, Vtb, bq, bk, bv,
                                       nullptr, nullptr, 0);

    dim3 g2(16, 64);  // q-tiles x (b*h)
    attn_kernel<<<g2, 256, 0, stream>>>(Qb, Kb2, Vtb, biasT, AO);

    dim3 g3(8, 32);   // N=1024 tiles x M=4096 tiles
    gemm_bt<1><<<g3, 256, 0, stream>>>(AO, wob, DM,
                                       nullptr, nullptr, nullptr,
                                       nullptr, nullptr, nullptr,
                                       out, bo, DM);
}